// Round 1
// baseline (3596.515 us; speedup 1.0000x reference)
//
#include <hip/hip_runtime.h>

#define N_NODES 50000
#define E_ADJ   800000
#define E_DEC   200000
#define FDIM    128
#define HDIM    64

// ---------------------------------------------------------------------------
// xw[k][n][h] = sum_f xin_k[n][f] * W[k][f][h],  k in 0..3
// xin_k = x0 for k even, x1 for k odd.
// One block per node row, 4 waves = 4 relations, lane = output column h.
// ---------------------------------------------------------------------------
template <int FIN>
__global__ void gemm_stage(const float* __restrict__ x0,
                           const float* __restrict__ x1,
                           const float* __restrict__ W,   // [4][FIN][HDIM]
                           float* __restrict__ xw)        // [4][N][HDIM]
{
    const int n    = blockIdx.x;
    const int wave = threadIdx.x >> 6;   // relation k (0..3)
    const int lane = threadIdx.x & 63;   // h

    __shared__ float s0[FIN];
    __shared__ float s1[FIN];
    for (int f = threadIdx.x; f < FIN; f += blockDim.x) {
        s0[f] = x0[(size_t)n * FIN + f];
        s1[f] = x1[(size_t)n * FIN + f];
    }
    __syncthreads();

    const float* xr = (wave & 1) ? s1 : s0;
    const float* Wk = W + (size_t)wave * FIN * HDIM;

    float acc = 0.f;
#pragma unroll 8
    for (int f = 0; f < FIN; ++f)
        acc += xr[f] * Wk[(size_t)f * HDIM + lane];

    xw[((size_t)wave * N_NODES + n) * HDIM + lane] = acc;
}

// ---------------------------------------------------------------------------
// y[k][r[e]][h] += xw[k][c[e]][h] * v[e]
// Thread layout: one wave (64 lanes) per edge; blockIdx.y = relation k.
// rows/cols/vals pointers are pre-offset to the 4-relation group.
// ---------------------------------------------------------------------------
__global__ void spmm_scatter(const int*   __restrict__ rows,  // [4][E]
                             const int*   __restrict__ cols,
                             const float* __restrict__ vals,
                             const float* __restrict__ xw,    // [4][N][H]
                             float*       __restrict__ y)     // [4][N][H]
{
    const int k = blockIdx.y;
    const long long t = (long long)blockIdx.x * blockDim.x + threadIdx.x;
    const int e = (int)(t >> 6);
    const int h = (int)(t & 63);
    if (e >= E_ADJ) return;

    const int   r = rows[(size_t)k * E_ADJ + e];
    const int   c = cols[(size_t)k * E_ADJ + e];
    const float v = vals[(size_t)k * E_ADJ + e];

    const float src = xw[((size_t)k * N_NODES + c) * HDIM + h];
    atomicAdd(&y[((size_t)k * N_NODES + r) * HDIM + h], src * v);
}

// ---------------------------------------------------------------------------
// h0 = relu(y0)+relu(y1);  h1 = relu(y2)+relu(y3)
// ---------------------------------------------------------------------------
__global__ void relu_sum(const float* __restrict__ y,   // [4][N][H]
                         float* __restrict__ h0,
                         float* __restrict__ h1)
{
    const size_t i = (size_t)blockIdx.x * blockDim.x + threadIdx.x;
    const size_t NH = (size_t)N_NODES * HDIM;
    if (i >= NH) return;
    const float a = fmaxf(y[i],          0.f);
    const float b = fmaxf(y[NH + i],     0.f);
    const float c = fmaxf(y[2 * NH + i], 0.f);
    const float d = fmaxf(y[3 * NH + i], 0.f);
    h0[i] = a + b;
    h1[i] = c + d;
}

// ---------------------------------------------------------------------------
// M[h][g] = d[h] * R[h][g] * d[g],  d = D_local[rt_k]
// ---------------------------------------------------------------------------
__global__ void make_M(const float* __restrict__ R,     // [H][H]
                       const float* __restrict__ Dl,    // [RT_NUM][H]
                       const int*   __restrict__ rt_k,
                       float* __restrict__ M)
{
    const int i = blockIdx.x * blockDim.x + threadIdx.x;
    if (i >= HDIM * HDIM) return;
    const float* d = Dl + rt_k[0] * HDIM;
    const int h = i >> 6;
    const int g = i & 63;
    M[i] = d[h] * R[i] * d[g];
}

// ---------------------------------------------------------------------------
// preds[e] = sum_{h,g} h0[i][h] * M[h][g] * h1[j][g]
// One wave per edge. Lane = g. s_g = sum_h er[h]*M[h][g] via shuffle-broadcast
// of er (LDS read sM[hh*64+lane] is consecutive across lanes: conflict-free).
// ---------------------------------------------------------------------------
__global__ void decode(const float* __restrict__ h0,
                       const float* __restrict__ h1,
                       const int*   __restrict__ edges,  // [E_DEC][2]
                       const float* __restrict__ M,
                       float* __restrict__ out)
{
    __shared__ float sM[HDIM * HDIM];
    for (int i = threadIdx.x; i < HDIM * HDIM; i += blockDim.x)
        sM[i] = M[i];
    __syncthreads();

    const long long t = (long long)blockIdx.x * blockDim.x + threadIdx.x;
    const int e    = (int)(t >> 6);
    const int lane = (int)(t & 63);
    if (e >= E_DEC) return;

    const int i = edges[2 * (size_t)e];
    const int j = edges[2 * (size_t)e + 1];

    const float er = h0[(size_t)i * HDIM + lane];
    const float ec = h1[(size_t)j * HDIM + lane];

    float s = 0.f;
#pragma unroll 8
    for (int hh = 0; hh < HDIM; ++hh) {
        const float erh = __shfl(er, hh, 64);
        s += erh * sM[hh * HDIM + lane];
    }
    float p = s * ec;
#pragma unroll
    for (int off = 32; off; off >>= 1)
        p += __shfl_down(p, off, 64);
    if (lane == 0) out[e] = p;
}

// ---------------------------------------------------------------------------
extern "C" void kernel_launch(void* const* d_in, const int* in_sizes, int n_in,
                              void* d_out, int out_size, void* d_ws, size_t ws_size,
                              hipStream_t stream) {
    const int*   adj_rows = (const int*)  d_in[0];
    const int*   adj_cols = (const int*)  d_in[1];
    const float* adj_vals = (const float*)d_in[2];
    const float* feat0    = (const float*)d_in[3];
    const float* feat1    = (const float*)d_in[4];
    const float* W1       = (const float*)d_in[5];
    const float* W2       = (const float*)d_in[6];
    const float* W3       = (const float*)d_in[7];
    const float* W4       = (const float*)d_in[8];
    const float* Rg       = (const float*)d_in[9];
    const float* Dl       = (const float*)d_in[10];
    const int*   edges    = (const int*)  d_in[11];
    const int*   rt_k     = (const int*)  d_in[12];
    float* out = (float*)d_out;

    const size_t NH = (size_t)N_NODES * HDIM;
    float* ws = (float*)d_ws;
    float* xw = ws;            // 4*NH
    float* y  = ws + 4 * NH;   // 4*NH
    float* h0 = ws + 8 * NH;   // NH
    float* h1 = ws + 9 * NH;   // NH
    float* M  = ws + 10 * NH;  // 4096
    // total: 10*NH + 4096 floats = 128.03 MB required in d_ws

    const dim3 spmm_grid(E_ADJ * HDIM / 256, 4);
    const int  relu_blocks = (int)(NH / 256);            // 12500 exactly
    const int  dec_blocks  = E_DEC * HDIM / 256;         // 50000 exactly

    // ---- stage 1: adjacency group 0, W1, inputs feat0/feat1 ----
    gemm_stage<FDIM><<<N_NODES, 256, 0, stream>>>(feat0, feat1, W1, xw);
    hipMemsetAsync(y, 0, 4 * NH * sizeof(float), stream);
    spmm_scatter<<<spmm_grid, 256, 0, stream>>>(adj_rows, adj_cols, adj_vals, xw, y);
    relu_sum<<<relu_blocks, 256, 0, stream>>>(y, h0, h1);

    // ---- stage 2: adjacency group 0, W2 ----
    gemm_stage<HDIM><<<N_NODES, 256, 0, stream>>>(h0, h1, W2, xw);
    hipMemsetAsync(y, 0, 4 * NH * sizeof(float), stream);
    spmm_scatter<<<spmm_grid, 256, 0, stream>>>(adj_rows, adj_cols, adj_vals, xw, y);
    relu_sum<<<relu_blocks, 256, 0, stream>>>(y, h0, h1);

    // ---- stage 3: adjacency group 1, W3 ----
    const int* r2 = adj_rows + 4 * (size_t)E_ADJ;
    const int* c2 = adj_cols + 4 * (size_t)E_ADJ;
    const float* v2 = adj_vals + 4 * (size_t)E_ADJ;
    gemm_stage<HDIM><<<N_NODES, 256, 0, stream>>>(h0, h1, W3, xw);
    hipMemsetAsync(y, 0, 4 * NH * sizeof(float), stream);
    spmm_scatter<<<spmm_grid, 256, 0, stream>>>(r2, c2, v2, xw, y);
    relu_sum<<<relu_blocks, 256, 0, stream>>>(y, h0, h1);

    // ---- stage 4: adjacency group 1, W4 ----
    gemm_stage<HDIM><<<N_NODES, 256, 0, stream>>>(h0, h1, W4, xw);
    hipMemsetAsync(y, 0, 4 * NH * sizeof(float), stream);
    spmm_scatter<<<spmm_grid, 256, 0, stream>>>(r2, c2, v2, xw, y);
    relu_sum<<<relu_blocks, 256, 0, stream>>>(y, h0, h1);

    // ---- decode ----
    make_M<<<(HDIM * HDIM + 255) / 256, 256, 0, stream>>>(Rg, Dl, rt_k, M);
    decode<<<dec_blocks, 256, 0, stream>>>(h0, h1, edges, M, out);
}

// Round 3
// 2369.918 us; speedup vs baseline: 1.5176x; 1.5176x over previous
//
#include <hip/hip_runtime.h>

#define N_NODES 50000
#define E_ADJ   800000
#define E_DEC   200000
#define FDIM    128
#define HDIM    64
#define NP1     (N_NODES + 1)
#define SCAN_NB 196            // ceil(50000/256)

// ---------------------------------------------------------------------------
// CSR build: histogram -> 3-phase exclusive scan -> scatter (counting sort)
// ---------------------------------------------------------------------------
__global__ void hist_kernel(const int* __restrict__ rows, int* __restrict__ counts)
{
    const int k = blockIdx.y;
    const int e = blockIdx.x * 256 + threadIdx.x;   // grid.x*256 == E_ADJ exactly
    const int r = rows[(size_t)k * E_ADJ + e];
    atomicAdd(&counts[k * N_NODES + r], 1);
}

__global__ void scan1(const int* __restrict__ counts,
                      int* __restrict__ row_ptr, int* __restrict__ blksums)
{
    const int k = blockIdx.y, b = blockIdx.x, tid = threadIdx.x;
    const int idx = b * 256 + tid;
    const int v = (idx < N_NODES) ? counts[k * N_NODES + idx] : 0;
    __shared__ int s[256];
    s[tid] = v;
    __syncthreads();
    for (int off = 1; off < 256; off <<= 1) {
        int t = (tid >= off) ? s[tid - off] : 0;
        __syncthreads();
        s[tid] += t;
        __syncthreads();
    }
    if (idx < N_NODES) row_ptr[k * NP1 + idx] = s[tid] - v;   // block-local exclusive
    if (tid == 255) blksums[k * SCAN_NB + b] = s[255];
}

__global__ void scan2(int* __restrict__ blksums)   // 1 block, 256 threads
{
    const int wave = threadIdx.x >> 6, lane = threadIdx.x & 63;
    if (wave < 4 && lane == 0) {
        int run = 0;
        for (int b = 0; b < SCAN_NB; ++b) {
            const int t = blksums[wave * SCAN_NB + b];
            blksums[wave * SCAN_NB + b] = run;
            run += t;
        }
    }
}

__global__ void scan3(int* __restrict__ row_ptr, const int* __restrict__ blksums,
                      int* __restrict__ wcur)
{
    const int k = blockIdx.y, b = blockIdx.x;
    const int idx = b * 256 + threadIdx.x;
    if (idx < N_NODES) {
        const int v = row_ptr[k * NP1 + idx] + blksums[k * SCAN_NB + b];
        row_ptr[k * NP1 + idx] = v;
        wcur[k * N_NODES + idx] = v;
    }
    if (idx == 0) row_ptr[k * NP1 + N_NODES] = E_ADJ;
}

__global__ void scatter_kernel(const int* __restrict__ rows,
                               const int* __restrict__ cols,
                               const float* __restrict__ vals,
                               int* __restrict__ wcur, float2* __restrict__ srt)
{
    const int k = blockIdx.y;
    const int e = blockIdx.x * 256 + threadIdx.x;
    const int r = rows[(size_t)k * E_ADJ + e];
    const int c = cols[(size_t)k * E_ADJ + e];
    const float v = vals[(size_t)k * E_ADJ + e];
    const int pos = atomicAdd(&wcur[k * N_NODES + r], 1);
    srt[(size_t)k * E_ADJ + pos] = make_float2(__int_as_float(c), v);
}

// ---------------------------------------------------------------------------
// xw[k][n][h] = sum_f xin_k[n][f] * W[k][f][h]; 8 rows per block, wave=relation.
// W traffic amortized 8x; x rows staged in LDS (broadcast reads).
// ---------------------------------------------------------------------------
template <int FIN>
__global__ void gemm_stage(const float* __restrict__ x0,
                           const float* __restrict__ x1,
                           const float* __restrict__ W,   // [4][FIN][HDIM]
                           float* __restrict__ xw)        // [4][N][HDIM]
{
    const int wave = threadIdx.x >> 6;   // relation k
    const int lane = threadIdx.x & 63;   // h
    const int n0 = blockIdx.x * 8;       // 6250 blocks * 8 = 50000 exactly

    __shared__ float sx[2][8][FIN];
    for (int i = threadIdx.x; i < 8 * FIN; i += 256) {
        const int r = i / FIN, f = i % FIN;
        sx[0][r][f] = x0[(size_t)(n0 + r) * FIN + f];
        sx[1][r][f] = x1[(size_t)(n0 + r) * FIN + f];
    }
    __syncthreads();

    const float* Wk = W + (size_t)wave * FIN * HDIM;
    const float (*xr)[FIN] = sx[wave & 1];

    float acc[8] = {0.f, 0.f, 0.f, 0.f, 0.f, 0.f, 0.f, 0.f};
#pragma unroll 4
    for (int f = 0; f < FIN; ++f) {
        const float w = Wk[(size_t)f * HDIM + lane];
#pragma unroll
        for (int r = 0; r < 8; ++r)
            acc[r] = fmaf(xr[r][f], w, acc[r]);
    }

    float* outp = xw + ((size_t)wave * N_NODES + n0) * HDIM + lane;
#pragma unroll
    for (int r = 0; r < 8; ++r)
        outp[(size_t)r * HDIM] = acc[r];
}

// ---------------------------------------------------------------------------
// Fused CSR-SPMM + relu + pairwise sum. Block = row n, wave = relation k.
// Each output written exactly once: no atomics, no y buffer, no memset.
// ---------------------------------------------------------------------------
__global__ void spmm_csr(const float2* __restrict__ srt,    // [4][E] {col,val}
                         const int*    __restrict__ row_ptr,// [4][N+1]
                         const float*  __restrict__ xw,     // [4][N][H]
                         float* __restrict__ h0, float* __restrict__ h1)
{
    const int k = threadIdx.x >> 6;
    const int lane = threadIdx.x & 63;
    const int n = blockIdx.x;

    const int s  = row_ptr[k * NP1 + n];
    const int en = row_ptr[k * NP1 + n + 1];
    const float2* sp = srt + (size_t)k * E_ADJ;
    const float*  xk = xw + (size_t)k * N_NODES * HDIM;

    float acc = 0.f;
    int e = s;
    if (e < en) {
        float2 cv = sp[e];
        ++e;
        for (; e < en; ++e) {
            const float2 nv = sp[e];   // prefetch next edge meta
            acc = fmaf(xk[(size_t)__float_as_int(cv.x) * HDIM + lane], cv.y, acc);
            cv = nv;
        }
        acc = fmaf(xk[(size_t)__float_as_int(cv.x) * HDIM + lane], cv.y, acc);
    }
    acc = fmaxf(acc, 0.f);

    __shared__ float sacc[4][HDIM];
    sacc[k][lane] = acc;
    __syncthreads();
    if (k == 0)      h0[(size_t)n * HDIM + lane] = sacc[0][lane] + sacc[1][lane];
    else if (k == 1) h1[(size_t)n * HDIM + lane] = sacc[2][lane] + sacc[3][lane];
}

// ---------------------------------------------------------------------------
__global__ void make_M(const float* __restrict__ R, const float* __restrict__ Dl,
                       const int* __restrict__ rt_k, float* __restrict__ M)
{
    const int i = blockIdx.x * blockDim.x + threadIdx.x;
    if (i >= HDIM * HDIM) return;
    const float* d = Dl + rt_k[0] * HDIM;
    M[i] = d[i >> 6] * R[i] * d[i & 63];
}

__global__ void decode(const float* __restrict__ h0, const float* __restrict__ h1,
                       const int* __restrict__ edges, const float* __restrict__ M,
                       float* __restrict__ out)
{
    __shared__ float sM[HDIM * HDIM];
    for (int i = threadIdx.x; i < HDIM * HDIM; i += blockDim.x)
        sM[i] = M[i];
    __syncthreads();

    const long long t = (long long)blockIdx.x * blockDim.x + threadIdx.x;
    const int e = (int)(t >> 6);
    const int lane = (int)(t & 63);
    if (e >= E_DEC) return;

    const int i = edges[2 * (size_t)e];
    const int j = edges[2 * (size_t)e + 1];
    const float er = h0[(size_t)i * HDIM + lane];
    const float ec = h1[(size_t)j * HDIM + lane];

    float s = 0.f;
#pragma unroll 8
    for (int hh = 0; hh < HDIM; ++hh)
        s += __shfl(er, hh, 64) * sM[hh * HDIM + lane];

    float p = s * ec;
#pragma unroll
    for (int off = 32; off; off >>= 1)
        p += __shfl_down(p, off, 64);
    if (lane == 0) out[e] = p;
}

// ---------------------------------------------------------------------------
static void build_csr(const int* rows, const int* cols, const float* vals,
                      int* counts, int* row_ptr, int* blksums, int* wcur,
                      float2* srt, hipStream_t stream)
{
    hipMemsetAsync(counts, 0, 4 * N_NODES * sizeof(int), stream);
    const dim3 eg(E_ADJ / 256, 4);
    const dim3 sg(SCAN_NB, 4);
    hist_kernel<<<eg, 256, 0, stream>>>(rows, counts);
    scan1<<<sg, 256, 0, stream>>>(counts, row_ptr, blksums);
    scan2<<<1, 256, 0, stream>>>(blksums);
    scan3<<<sg, 256, 0, stream>>>(row_ptr, blksums, wcur);
    scatter_kernel<<<eg, 256, 0, stream>>>(rows, cols, vals, wcur, srt);
}

extern "C" void kernel_launch(void* const* d_in, const int* in_sizes, int n_in,
                              void* d_out, int out_size, void* d_ws, size_t ws_size,
                              hipStream_t stream) {
    const int*   adj_rows = (const int*)  d_in[0];
    const int*   adj_cols = (const int*)  d_in[1];
    const float* adj_vals = (const float*)d_in[2];
    const float* feat0    = (const float*)d_in[3];
    const float* feat1    = (const float*)d_in[4];
    const float* W1       = (const float*)d_in[5];
    const float* W2       = (const float*)d_in[6];
    const float* W3       = (const float*)d_in[7];
    const float* W4       = (const float*)d_in[8];
    const float* Rg       = (const float*)d_in[9];
    const float* Dl       = (const float*)d_in[10];
    const int*   edges    = (const int*)  d_in[11];
    const int*   rt_k     = (const int*)  d_in[12];
    float* out = (float*)d_out;

    const size_t NH = (size_t)N_NODES * HDIM;
    float* ws = (float*)d_ws;
    float*  xw      = ws;                         // 4*NH          = 12,800,000 f
    float*  h0      = xw + 4 * NH;                // NH
    float*  h1      = h0 + NH;                    // NH
    float2* srt     = (float2*)(h1 + NH);         // 4*E float2    = 6,400,000 f
    int*    row_ptr = (int*)(h1 + NH + 8 * (size_t)E_ADJ); // 4*(N+1)
    int*    wcur    = row_ptr + 4 * NP1 + 60;     // pad; 4*N
    int*    counts  = wcur + 4 * N_NODES;         // 4*N
    int*    blksums = counts + 4 * N_NODES;       // 4*SCAN_NB
    float*  M       = (float*)(blksums + 4 * SCAN_NB + 48); // 4096 f
    // total ~= 26.2M floats ~= 105 MB

    const int* r2 = adj_rows + 4 * (size_t)E_ADJ;
    const int* c2 = adj_cols + 4 * (size_t)E_ADJ;
    const float* v2 = adj_vals + 4 * (size_t)E_ADJ;

    // ---- CSR for adjacency group A (stages 1 & 2) ----
    build_csr(adj_rows, adj_cols, adj_vals, counts, row_ptr, blksums, wcur, srt, stream);

    // ---- stage 1 ----
    gemm_stage<FDIM><<<N_NODES / 8, 256, 0, stream>>>(feat0, feat1, W1, xw);
    spmm_csr<<<N_NODES, 256, 0, stream>>>(srt, row_ptr, xw, h0, h1);

    // ---- stage 2 ----
    gemm_stage<HDIM><<<N_NODES / 8, 256, 0, stream>>>(h0, h1, W2, xw);
    spmm_csr<<<N_NODES, 256, 0, stream>>>(srt, row_ptr, xw, h0, h1);

    // ---- CSR for adjacency group B (stages 3 & 4), same buffers ----
    build_csr(r2, c2, v2, counts, row_ptr, blksums, wcur, srt, stream);

    // ---- stage 3 ----
    gemm_stage<HDIM><<<N_NODES / 8, 256, 0, stream>>>(h0, h1, W3, xw);
    spmm_csr<<<N_NODES, 256, 0, stream>>>(srt, row_ptr, xw, h0, h1);

    // ---- stage 4 ----
    gemm_stage<HDIM><<<N_NODES / 8, 256, 0, stream>>>(h0, h1, W4, xw);
    spmm_csr<<<N_NODES, 256, 0, stream>>>(srt, row_ptr, xw, h0, h1);

    // ---- decode ----
    make_M<<<(HDIM * HDIM + 255) / 256, 256, 0, stream>>>(Rg, Dl, rt_k, M);
    decode<<<E_DEC * HDIM / 256, 256, 0, stream>>>(h0, h1, edges, M, out);
}

// Round 7
// 1474.547 us; speedup vs baseline: 2.4391x; 1.6072x over previous
//
#include <hip/hip_runtime.h>

#define N_NODES 50000
#define E_ADJ   800000
#define E_DEC   200000
#define FDIM    128
#define HDIM    64
#define NP1     (N_NODES + 1)
#define SCAN_NB 196            // ceil(50000/256)

// ---------------------------------------------------------------------------
// CSR build: histogram -> 3-phase exclusive scan -> scatter (counting sort)
// ---------------------------------------------------------------------------
__global__ void hist_kernel(const int* __restrict__ rows, int* __restrict__ counts)
{
    const int k = blockIdx.y;
    const int e = blockIdx.x * 256 + threadIdx.x;   // grid.x*256 == E_ADJ exactly
    const int r = rows[(size_t)k * E_ADJ + e];
    atomicAdd(&counts[k * N_NODES + r], 1);
}

__global__ void scan1(const int* __restrict__ counts,
                      int* __restrict__ row_ptr, int* __restrict__ blksums)
{
    const int k = blockIdx.y, b = blockIdx.x, tid = threadIdx.x;
    const int idx = b * 256 + tid;
    const int v = (idx < N_NODES) ? counts[k * N_NODES + idx] : 0;
    __shared__ int s[256];
    s[tid] = v;
    __syncthreads();
    for (int off = 1; off < 256; off <<= 1) {
        int t = (tid >= off) ? s[tid - off] : 0;
        __syncthreads();
        s[tid] += t;
        __syncthreads();
    }
    if (idx < N_NODES) row_ptr[k * NP1 + idx] = s[tid] - v;   // block-local exclusive
    if (tid == 255) blksums[k * SCAN_NB + b] = s[255];
}

__global__ void scan2(int* __restrict__ blksums)   // 1 block, 256 threads
{
    const int wave = threadIdx.x >> 6, lane = threadIdx.x & 63;
    if (wave < 4 && lane == 0) {
        int run = 0;
        for (int b = 0; b < SCAN_NB; ++b) {
            const int t = blksums[wave * SCAN_NB + b];
            blksums[wave * SCAN_NB + b] = run;
            run += t;
        }
    }
}

__global__ void scan3(int* __restrict__ row_ptr, const int* __restrict__ blksums,
                      int* __restrict__ wcur)
{
    const int k = blockIdx.y, b = blockIdx.x;
    const int idx = b * 256 + threadIdx.x;
    if (idx < N_NODES) {
        const int v = row_ptr[k * NP1 + idx] + blksums[k * SCAN_NB + b];
        row_ptr[k * NP1 + idx] = v;
        wcur[k * N_NODES + idx] = v;
    }
    if (idx == 0) row_ptr[k * NP1 + N_NODES] = E_ADJ;
}

__global__ void scatter_kernel(const int* __restrict__ rows,
                               const int* __restrict__ cols,
                               const float* __restrict__ vals,
                               int* __restrict__ wcur, float2* __restrict__ srt)
{
    const int k = blockIdx.y;
    const int e = blockIdx.x * 256 + threadIdx.x;
    const int r = rows[(size_t)k * E_ADJ + e];
    const int c = cols[(size_t)k * E_ADJ + e];
    const float v = vals[(size_t)k * E_ADJ + e];
    const int pos = atomicAdd(&wcur[k * N_NODES + r], 1);
    srt[(size_t)k * E_ADJ + pos] = make_float2(__int_as_float(c), v);
}

// ---------------------------------------------------------------------------
// xw[k][n][h] = sum_f xin_k[n][f] * W[k][f][h]; 8 rows per block, wave=relation.
// ---------------------------------------------------------------------------
template <int FIN>
__global__ void gemm_stage(const float* __restrict__ x0,
                           const float* __restrict__ x1,
                           const float* __restrict__ W,   // [4][FIN][HDIM]
                           float* __restrict__ xw)        // [4][N][HDIM]
{
    const int wave = threadIdx.x >> 6;   // relation k
    const int lane = threadIdx.x & 63;   // h
    const int n0 = blockIdx.x * 8;       // 6250 blocks * 8 = 50000 exactly

    __shared__ float sx[2][8][FIN];
    for (int i = threadIdx.x; i < 8 * FIN; i += 256) {
        const int r = i / FIN, f = i % FIN;
        sx[0][r][f] = x0[(size_t)(n0 + r) * FIN + f];
        sx[1][r][f] = x1[(size_t)(n0 + r) * FIN + f];
    }
    __syncthreads();

    const float* Wk = W + (size_t)wave * FIN * HDIM;
    const float (*xr)[FIN] = sx[wave & 1];

    float acc[8] = {0.f, 0.f, 0.f, 0.f, 0.f, 0.f, 0.f, 0.f};
#pragma unroll 4
    for (int f = 0; f < FIN; ++f) {
        const float w = Wk[(size_t)f * HDIM + lane];
#pragma unroll
        for (int r = 0; r < 8; ++r)
            acc[r] = fmaf(xr[r][f], w, acc[r]);
    }

    float* outp = xw + ((size_t)wave * N_NODES + n0) * HDIM + lane;
#pragma unroll
    for (int r = 0; r < 8; ++r)
        outp[(size_t)r * HDIM] = acc[r];
}

// ---------------------------------------------------------------------------
// Fused CSR-SPMM + relu + pairwise sum. Block = row n, wave = relation k.
// v2: coalesced edge-meta load per 64-edge chunk + 8-way independent gathers
// (8 accumulators) for memory-level parallelism.
// ---------------------------------------------------------------------------
__global__ void spmm_csr(const float2* __restrict__ srt,    // [4][E] {col,val}
                         const int*    __restrict__ row_ptr,// [4][N+1]
                         const float*  __restrict__ xw,     // [4][N][H]
                         float* __restrict__ h0, float* __restrict__ h1)
{
    const int k = threadIdx.x >> 6;
    const int lane = threadIdx.x & 63;
    const int n = blockIdx.x;

    const int s  = row_ptr[k * NP1 + n];
    const int en = row_ptr[k * NP1 + n + 1];
    const float2* sp = srt + (size_t)k * E_ADJ;
    const float*  xk = xw + (size_t)k * N_NODES * HDIM;

    float a[8] = {0.f, 0.f, 0.f, 0.f, 0.f, 0.f, 0.f, 0.f};

    for (int base = s; base < en; base += 64) {
        const int cnt = min(64, en - base);
        float2 meta = make_float2(0.f, 0.f);
        if (lane < cnt) meta = sp[base + lane];   // one coalesced meta load

        int j = 0;
        for (; j + 8 <= cnt; j += 8) {
            int   c[8];
            float v[8], g[8];
#pragma unroll
            for (int u = 0; u < 8; ++u) {
                c[u] = __shfl(__float_as_int(meta.x), j + u, 64);
                v[u] = __shfl(meta.y, j + u, 64);
            }
#pragma unroll
            for (int u = 0; u < 8; ++u)           // 8 independent gathers in flight
                g[u] = xk[(size_t)c[u] * HDIM + lane];
#pragma unroll
            for (int u = 0; u < 8; ++u)
                a[u] = fmaf(g[u], v[u], a[u]);
        }
        for (; j < cnt; ++j) {
            const int   cc = __shfl(__float_as_int(meta.x), j, 64);
            const float vv = __shfl(meta.y, j, 64);
            a[0] = fmaf(xk[(size_t)cc * HDIM + lane], vv, a[0]);
        }
    }

    float acc = ((a[0] + a[1]) + (a[2] + a[3])) + ((a[4] + a[5]) + (a[6] + a[7]));
    acc = fmaxf(acc, 0.f);

    __shared__ float sacc[4][HDIM];
    sacc[k][lane] = acc;
    __syncthreads();
    if (k == 0)      h0[(size_t)n * HDIM + lane] = sacc[0][lane] + sacc[1][lane];
    else if (k == 1) h1[(size_t)n * HDIM + lane] = sacc[2][lane] + sacc[3][lane];
}

// ---------------------------------------------------------------------------
__global__ void make_M(const float* __restrict__ R, const float* __restrict__ Dl,
                       const int* __restrict__ rt_k, float* __restrict__ M)
{
    const int i = blockIdx.x * blockDim.x + threadIdx.x;
    if (i >= HDIM * HDIM) return;
    const float* d = Dl + rt_k[0] * HDIM;
    M[i] = d[i >> 6] * R[i] * d[i & 63];
}

// A[n][g] = sum_h h0[n][h] * M[h][g]   (16 rows/block, 4 waves x 4 rows)
__global__ void h0M_kernel(const float* __restrict__ h0, const float* __restrict__ M,
                           float* __restrict__ A)
{
    const int wave = threadIdx.x >> 6, lane = threadIdx.x & 63;
    const int n0 = blockIdx.x * 16;      // 3125 blocks * 16 = 50000 exactly

    __shared__ float sx[16][HDIM];
    for (int i = threadIdx.x; i < 16 * HDIM; i += 256)
        sx[i >> 6][i & 63] = h0[(size_t)n0 * HDIM + i];
    __syncthreads();

    float acc[4] = {0.f, 0.f, 0.f, 0.f};
#pragma unroll 4
    for (int f = 0; f < HDIM; ++f) {
        const float w = M[f * HDIM + lane];
#pragma unroll
        for (int r = 0; r < 4; ++r)
            acc[r] = fmaf(sx[wave * 4 + r][f], w, acc[r]);
    }
#pragma unroll
    for (int r = 0; r < 4; ++r)
        A[(size_t)(n0 + wave * 4 + r) * HDIM + lane] = acc[r];
}

// preds[e] = dot(A[i], h1[j]) — one wave per edge, 64-wide dot + reduce.
__global__ void decode(const float* __restrict__ A, const float* __restrict__ h1,
                       const int* __restrict__ edges, float* __restrict__ out)
{
    const long long t = (long long)blockIdx.x * 256 + threadIdx.x;
    const int e = (int)(t >> 6);
    const int lane = (int)(t & 63);

    const int i = edges[2 * (size_t)e];
    const int j = edges[2 * (size_t)e + 1];

    float p = A[(size_t)i * HDIM + lane] * h1[(size_t)j * HDIM + lane];
#pragma unroll
    for (int off = 32; off; off >>= 1)
        p += __shfl_down(p, off, 64);
    if (lane == 0) out[e] = p;
}

// ---------------------------------------------------------------------------
static void build_csr(const int* rows, const int* cols, const float* vals,
                      int* counts, int* row_ptr, int* blksums, int* wcur,
                      float2* srt, hipStream_t stream)
{
    hipMemsetAsync(counts, 0, 4 * N_NODES * sizeof(int), stream);
    const dim3 eg(E_ADJ / 256, 4);
    const dim3 sg(SCAN_NB, 4);
    hist_kernel<<<eg, 256, 0, stream>>>(rows, counts);
    scan1<<<sg, 256, 0, stream>>>(counts, row_ptr, blksums);
    scan2<<<1, 256, 0, stream>>>(blksums);
    scan3<<<sg, 256, 0, stream>>>(row_ptr, blksums, wcur);
    scatter_kernel<<<eg, 256, 0, stream>>>(rows, cols, vals, wcur, srt);
}

extern "C" void kernel_launch(void* const* d_in, const int* in_sizes, int n_in,
                              void* d_out, int out_size, void* d_ws, size_t ws_size,
                              hipStream_t stream) {
    const int*   adj_rows = (const int*)  d_in[0];
    const int*   adj_cols = (const int*)  d_in[1];
    const float* adj_vals = (const float*)d_in[2];
    const float* feat0    = (const float*)d_in[3];
    const float* feat1    = (const float*)d_in[4];
    const float* W1       = (const float*)d_in[5];
    const float* W2       = (const float*)d_in[6];
    const float* W3       = (const float*)d_in[7];
    const float* W4       = (const float*)d_in[8];
    const float* Rg       = (const float*)d_in[9];
    const float* Dl       = (const float*)d_in[10];
    const int*   edges    = (const int*)  d_in[11];
    const int*   rt_k     = (const int*)  d_in[12];
    float* out = (float*)d_out;

    const size_t NH = (size_t)N_NODES * HDIM;
    float* ws = (float*)d_ws;
    float*  xw      = ws;                         // 4*NH  (reused as A at the end)
    float*  h0      = xw + 4 * NH;                // NH
    float*  h1      = h0 + NH;                    // NH
    float2* srt     = (float2*)(h1 + NH);         // 4*E float2
    int*    row_ptr = (int*)(h1 + NH + 8 * (size_t)E_ADJ); // 4*(N+1)
    int*    wcur    = row_ptr + 4 * NP1 + 60;     // pad; 4*N
    int*    counts  = wcur + 4 * N_NODES;         // 4*N
    int*    blksums = counts + 4 * N_NODES;       // 4*SCAN_NB
    float*  M       = (float*)(blksums + 4 * SCAN_NB + 48); // 4096 f
    // total ~= 26.2M floats ~= 105 MB

    const int* r2 = adj_rows + 4 * (size_t)E_ADJ;
    const int* c2 = adj_cols + 4 * (size_t)E_ADJ;
    const float* v2 = adj_vals + 4 * (size_t)E_ADJ;

    // ---- CSR for adjacency group A (stages 1 & 2) ----
    build_csr(adj_rows, adj_cols, adj_vals, counts, row_ptr, blksums, wcur, srt, stream);

    // ---- stage 1 ----
    gemm_stage<FDIM><<<N_NODES / 8, 256, 0, stream>>>(feat0, feat1, W1, xw);
    spmm_csr<<<N_NODES, 256, 0, stream>>>(srt, row_ptr, xw, h0, h1);

    // ---- stage 2 ----
    gemm_stage<HDIM><<<N_NODES / 8, 256, 0, stream>>>(h0, h1, W2, xw);
    spmm_csr<<<N_NODES, 256, 0, stream>>>(srt, row_ptr, xw, h0, h1);

    // ---- CSR for adjacency group B (stages 3 & 4) ----
    build_csr(r2, c2, v2, counts, row_ptr, blksums, wcur, srt, stream);

    // ---- stage 3 ----
    gemm_stage<HDIM><<<N_NODES / 8, 256, 0, stream>>>(h0, h1, W3, xw);
    spmm_csr<<<N_NODES, 256, 0, stream>>>(srt, row_ptr, xw, h0, h1);

    // ---- stage 4 ----
    gemm_stage<HDIM><<<N_NODES / 8, 256, 0, stream>>>(h0, h1, W4, xw);
    spmm_csr<<<N_NODES, 256, 0, stream>>>(srt, row_ptr, xw, h0, h1);

    // ---- decode: M, A = h0@M (A aliases xw, now free), dot per edge ----
    make_M<<<(HDIM * HDIM + 255) / 256, 256, 0, stream>>>(Rg, Dl, rt_k, M);
    float* A = xw;
    h0M_kernel<<<N_NODES / 16, 256, 0, stream>>>(h0, M, A);
    decode<<<E_DEC * HDIM / 256, 256, 0, stream>>>(A, h1, edges, out);
}